// Round 20
// baseline (84.358 us; speedup 1.0000x reference)
//
#include <hip/hip_runtime.h>
#include <hip/hip_bf16.h>
#include <hip/hip_fp16.h>
#include <math.h>

#define NB 8
#define LL 8192
#define DD 64
#define NS 11
#define NR 4
#define NC 512        // chunks
#define LC (LL/NC)    // 16 positions per chunk
#define CONV_LT 128
#define KW 63
#define PJ 64         // proj tile = 4 chunks
#define NBKT 64       // BN atomic buckets
#define UH 72         // half stride for ulh rows (144B per row, 16B aligned)
#define WS 72         // LDS row stride for wsh2 (f32)

__device__ __forceinline__ float sigmoidf_(float v){ return 1.f/(1.f+__expf(-v)); }
__device__ __forceinline__ float rnd16(float v){ return __half2float(__float2half_rn(v)); }

// ---------------- K0: zero the BN accumulator ----------------
__global__ void k_zero(float* __restrict__ p){
  p[blockIdx.x*256 + threadIdx.x] = 0.f;
}

// ---------------- K1: depthwise conv (k=63, pad 31) + bucketed BN partial sums ------
__global__ __launch_bounds__(512,4) void k_conv(const float* __restrict__ x,
                                              const float* __restrict__ w,
                                              __half* __restrict__ xc,
                                              float* __restrict__ bn_acc){
  const int b  = blockIdx.x / (LL/CONV_LT);
  const int lt = blockIdx.x % (LL/CONV_LT);
  const int l0 = lt*CONV_LT;
  __shared__ float xt[(CONV_LT+62)*DD];   // 47.5 KB
  __shared__ float rs[512], rq[512];
  const int t = threadIdx.x;
  for (int i=t; i<(CONV_LT+62)*DD; i+=512){
    int lrel = i/DD, d = i%DD;
    int lg = l0 - 31 + lrel;
    xt[i] = (lg>=0 && lg<LL) ? x[((size_t)b*LL+lg)*DD + d] : 0.f;
  }
  __syncthreads();
  const int d = t & 63;
  const int base = (t >> 6) * 16;       // 8 waves x 16 positions
  float acc[16];
  #pragma unroll
  for (int j=0;j<16;j++) acc[j]=0.f;
  #pragma unroll 1
  for (int kb=0; kb<4; ++kb){
    float wv[16];
    #pragma unroll
    for (int kk=0;kk<16;kk++){
      int k = kb*16+kk;
      wv[kk] = (k<KW) ? w[d*KW+k] : 0.f;
    }
    float xw[31];
    #pragma unroll
    for (int i=0;i<31;i++) xw[i] = xt[(base+kb*16+i)*DD + d];
    #pragma unroll
    for (int j=0;j<16;j++){
      #pragma unroll
      for (int kk=0;kk<16;kk++){
        acc[j] = fmaf(wv[kk], xw[j+kk], acc[j]);
      }
    }
  }
  float lsum=0.f, lsq=0.f;
  #pragma unroll
  for (int j=0;j<16;j++){
    xc[((size_t)b*LL + l0+base+j)*DD + d] = __float2half_rn(acc[j]);
    lsum += acc[j]; lsq = fmaf(acc[j],acc[j],lsq);
  }
  rs[t]=lsum; rq[t]=lsq;
  __syncthreads();
  if (t<64){
    float s=0.f, q=0.f;
    #pragma unroll
    for (int g=0; g<8; ++g){ s += rs[t+64*g]; q += rq[t+64*g]; }
    const int bkt = (blockIdx.x & (NBKT-1))*128;
    atomicAdd(&bn_acc[bkt+t],    s);
    atomicAdd(&bn_acc[bkt+64+t], q);
  }
}

// ---------------- K2: BN+SiLU ; x_proj (half2 u) ; packed bch ; merged scan ---------
__global__ __launch_bounds__(256,5) void k_proj(const __half* __restrict__ xc,
                                              const float* __restrict__ bn_acc,
                                              const float* __restrict__ gamma,
                                              const float* __restrict__ beta,
                                              const float* __restrict__ xpw,
                                              const float* __restrict__ dtw,
                                              const float* __restrict__ dtb,
                                              const float* __restrict__ Alog,
                                              __half2* __restrict__ duo,
                                              __half* __restrict__ bch,
                                              float* __restrict__ chunkst){
  const int b  = blockIdx.x / (LL/PJ);
  const int lt = blockIdx.x % (LL/PJ);
  const int l0 = lt*PJ;
  __shared__ __align__(16) __half ulh[PJ*UH];   // 9.2 KB (u, fp16-exact)
  __shared__ float bcl[PJ][24];        // 6 KB
  __shared__ float wsh2[26*WS];        // 7.3 KB
  __shared__ float xd[PJ*NR];          // 1 KB
  __shared__ float dtwsh[64*NR];       // 1 KB
  __shared__ float bnred[2][4][64];    // 2 KB
  const int t = threadIdx.x;
  for (int i=t; i<26*64; i+=256){ int c=i>>6, dd=i&63; wsh2[c*WS+dd] = xpw[i]; }
  dtwsh[t] = dtw[t];
  if (t < 128){ bcl[t>>1][(t&1)?23:11] = 0.f; }   // zero pad slots for pack phase
  const int d = t & 63, wv = t >> 6;
  {
    float ms=0.f, qs=0.f;
    #pragma unroll
    for (int k=wv*16; k<wv*16+16; ++k){
      ms += bn_acc[k*128 + d];
      qs += bn_acc[k*128 + 64 + d];
    }
    bnred[0][wv][d]=ms; bnred[1][wv][d]=qs;
  }
  __syncthreads();
  float msum = bnred[0][0][d]+bnred[0][1][d]+bnred[0][2][d]+bnred[0][3][d];
  float qsum = bnred[1][0][d]+bnred[1][1][d]+bnred[1][2][d]+bnred[1][3][d];
  const float inv_n = 1.f/((float)NB*(float)LL);
  float mean = msum*inv_n;
  float var  = qsum*inv_n - mean*mean;
  float sc = gamma[d] * rsqrtf(var + 1e-5f);
  float sh = beta[d] - mean*sc;
  float uu[16];
  #pragma unroll
  for (int j=0;j<16;j++){
    int lr = wv*16 + j;
    float v = __half2float(xc[((size_t)b*LL + l0+lr)*DD + d]);
    v = fmaf(v, sc, sh);
    __half uh = __float2half_rn(v * sigmoidf_(v));
    uu[j] = __half2float(uh);          // fp16-consistent with scanB
    ulh[lr*UH+d] = uh;
  }
  __syncthreads();
  // x_proj matvec: 2 cols x 4 pos x 8-dd blocking; u read as 8xfp16 per b128
  {
    const int cp  = t & 15;
    const int lrb = t >> 4;
    if (cp < 13){
      float acc0[4] = {0.f,0.f,0.f,0.f};
      float acc1[4] = {0.f,0.f,0.f,0.f};
      #pragma unroll 2
      for (int dd8=0; dd8<8; ++dd8){
        float4 w0a = *reinterpret_cast<const float4*>(&wsh2[(2*cp  )*WS + dd8*8]);
        float4 w0b = *reinterpret_cast<const float4*>(&wsh2[(2*cp  )*WS + dd8*8+4]);
        float4 w1a = *reinterpret_cast<const float4*>(&wsh2[(2*cp+1)*WS + dd8*8]);
        float4 w1b = *reinterpret_cast<const float4*>(&wsh2[(2*cp+1)*WS + dd8*8+4]);
        #pragma unroll
        for (int p=0;p<4;p++){
          float4 uvv = *reinterpret_cast<const float4*>(&ulh[(lrb*4+p)*UH + dd8*8]);
          const __half2* uh2 = reinterpret_cast<const __half2*>(&uvv);
          float2 f0 = __half22float2(uh2[0]);
          float2 f1 = __half22float2(uh2[1]);
          float2 f2 = __half22float2(uh2[2]);
          float2 f3 = __half22float2(uh2[3]);
          acc0[p] = fmaf(w0a.x,f0.x, fmaf(w0a.y,f0.y, fmaf(w0a.z,f1.x, fmaf(w0a.w,f1.y, acc0[p]))));
          acc0[p] = fmaf(w0b.x,f2.x, fmaf(w0b.y,f2.y, fmaf(w0b.z,f3.x, fmaf(w0b.w,f3.y, acc0[p]))));
          acc1[p] = fmaf(w1a.x,f0.x, fmaf(w1a.y,f0.y, fmaf(w1a.z,f1.x, fmaf(w1a.w,f1.y, acc1[p]))));
          acc1[p] = fmaf(w1b.x,f2.x, fmaf(w1b.y,f2.y, fmaf(w1b.z,f3.x, fmaf(w1b.w,f3.y, acc1[p]))));
        }
      }
      #pragma unroll
      for (int cc=0; cc<2; ++cc){
        int c = 2*cp+cc;
        #pragma unroll
        for (int p=0;p<4;p++){
          int lr = lrb*4+p;
          float v = cc ? acc1[p] : acc0[p];
          if (c < NR) xd[lr*NR+c] = v;
          else {
            int pos = c - NR;                       // B:0..10  C:11..21
            int slot = (pos < NS) ? pos : pos+1;    // pad slots 11 and 23
            bcl[lr][slot] = rnd16(v);               // fp16-consistent
          }
        }
      }
    }
  }
  __syncthreads();
  // coalesced bch pack: 64 pos x 24 half = 768 half2; thread t writes 3
  {
    __half2* dst = reinterpret_cast<__half2*>(bch + ((size_t)b*LL + l0)*24);
    #pragma unroll
    for (int r=0;r<3;r++){
      int j = t + 256*r;                 // half2 index 0..767
      int pos = j / 12, sl = (j % 12)*2;
      dst[j] = __floats2half2_rn(bcl[pos][sl], bcl[pos][sl+1]);
    }
  }
  // merged dt-proj + softplus + duo(half2) store + chunk-local scan
  {
    const float bias = dtb[d];
    const float dw0 = dtwsh[d*NR+0], dw1 = dtwsh[d*NR+1],
                dw2 = dtwsh[d*NR+2], dw3 = dtwsh[d*NR+3];
    float a0 = -__expf(Alog[d*NS]);
    bool fast = true;
    #pragma unroll
    for (int n=1;n<NS;n++){
      float an = -__expf(Alog[d*NS+n]);
      fast = fast && (fabsf(an - (float)(n+1)*a0) <= 1e-4f*(float)(n+1));
    }
    const int task = b*NC + lt*4 + wv;
    float h[12];
    #pragma unroll
    for (int n=0;n<12;n++) h[n]=0.f;
    float dsum=0.f;
    #pragma unroll 4
    for (int l=0;l<LC;++l){
      int lr = wv*LC + l;
      float4 xv = *reinterpret_cast<const float4*>(&xd[lr*NR]);
      float s = fmaf(dw0,xv.x, fmaf(dw1,xv.y, fmaf(dw2,xv.z, fmaf(dw3,xv.w, bias))));
      float de = rnd16(fmaxf(s,0.f) + __logf(1.f + __expf(-fabsf(s))));
      float u_ = uu[l];
      float du = de*u_;
      dsum += de;
      duo[((size_t)b*LL + l0+lr)*DD + d] = __floats2half2_rn(de, u_);
      float bca[12];
      const float4* q = reinterpret_cast<const float4*>(&bcl[lr][0]);
      *reinterpret_cast<float4*>(&bca[0]) = q[0];
      *reinterpret_cast<float4*>(&bca[4]) = q[1];
      *reinterpret_cast<float4*>(&bca[8]) = q[2];
      if (fast){
        float r = __expf(a0*de);
        float dA = 1.f;
        #pragma unroll
        for (int n=0;n<NS;n++){
          dA *= r;
          h[n] = fmaf(dA, h[n], du*bca[n]);
        }
      } else {
        #pragma unroll
        for (int n=0;n<NS;n++){
          float dA = __expf(-__expf(Alog[d*NS+n])*de);
          h[n] = fmaf(dA, h[n], du*bca[n]);
        }
      }
    }
    h[11] = dsum;
    float4* o = reinterpret_cast<float4*>(chunkst + ((size_t)task*64 + d)*12);
    o[0] = *reinterpret_cast<float4*>(&h[0]);
    o[1] = *reinterpret_cast<float4*>(&h[4]);
    o[2] = *reinterpret_cast<float4*>(&h[8]);
  }
}

// ---------------- K4: cross-chunk propagation — one wave per (b,d), recs in regs ----
__global__ __launch_bounds__(64) void k_scanMid(const float* __restrict__ chunkst,
                                                const float* __restrict__ Alog,
                                                float* __restrict__ hin){
  const int wid  = blockIdx.x;
  const int lane = threadIdx.x & 63;
  const int b = wid >> 6, d = wid & 63;
  const int c0 = lane*8;
  const size_t recbase = (((size_t)b*NC + c0)*64 + d)*12;
  float rec[8][12];
  #pragma unroll
  for (int j=0;j<8;j++){
    const float4* q = reinterpret_cast<const float4*>(chunkst + recbase + (size_t)j*768);
    *reinterpret_cast<float4*>(&rec[j][0]) = q[0];
    *reinterpret_cast<float4*>(&rec[j][4]) = q[1];
    *reinterpret_cast<float4*>(&rec[j][8]) = q[2];
  }
  float aAll[NS];
  #pragma unroll
  for (int n=0;n<NS;n++) aAll[n] = -expf(Alog[d*NS+n]);
  bool fast = true;
  #pragma unroll
  for (int n=1;n<NS;n++)
    fast = fast && (fabsf(aAll[n] - (float)(n+1)*aAll[0]) <= 1e-4f*(float)(n+1));
  float Aa[NS], Bb[NS];
  #pragma unroll
  for (int n=0;n<NS;n++){ Aa[n]=1.f; Bb[n]=0.f; }
  #pragma unroll
  for (int j=0;j<8;j++){
    float ds = rec[j][11];
    if (fast){
      float r = __expf(aAll[0]*ds);
      float dA = 1.f;
      #pragma unroll
      for (int n=0;n<NS;n++){
        dA *= r;
        Bb[n] = fmaf(dA, Bb[n], rec[j][n]);
        Aa[n] *= dA;
      }
    } else {
      #pragma unroll
      for (int n=0;n<NS;n++){
        float dA = __expf(aAll[n]*ds);
        Bb[n] = fmaf(dA, Bb[n], rec[j][n]);
        Aa[n] *= dA;
      }
    }
  }
  #pragma unroll
  for (int n=0;n<NS;n++){
    float A = Aa[n], Bv = Bb[n];
    #pragma unroll
    for (int off=1; off<64; off<<=1){
      float Ap=__shfl_up(A,off,64), Bp=__shfl_up(Bv,off,64);
      if (lane>=off){ Bv = fmaf(A,Bp,Bv); A*=Ap; }
    }
    float hs = __shfl_up(Bv,1,64);
    Bb[n] = (lane==0) ? 0.f : hs;
  }
  #pragma unroll
  for (int j=0;j<8;j++){
    float ds = rec[j][11];
    float outv[12];
    if (fast){
      float r = __expf(aAll[0]*ds);
      float dA = 1.f;
      #pragma unroll
      for (int n=0;n<NS;n++){
        outv[n] = Bb[n];
        dA *= r;
        Bb[n] = fmaf(dA, Bb[n], rec[j][n]);
      }
    } else {
      #pragma unroll
      for (int n=0;n<NS;n++){
        outv[n] = Bb[n];
        float dA = __expf(aAll[n]*ds);
        Bb[n] = fmaf(dA, Bb[n], rec[j][n]);
      }
    }
    outv[11] = 0.f;
    float4* o = reinterpret_cast<float4*>(hin + recbase + (size_t)j*768);
    o[0] = *reinterpret_cast<float4*>(&outv[0]);
    o[1] = *reinterpret_cast<float4*>(&outv[4]);
    o[2] = *reinterpret_cast<float4*>(&outv[8]);
  }
}

// ---------------- K5: replay scan, 4-position load tiling, RMSNorm, SiLU gate ------
__global__ __launch_bounds__(256,4) void k_scanB(const __half2* __restrict__ duo,
                                               const __half* __restrict__ bch,
                                               const float* __restrict__ Alog,
                                               const float* __restrict__ hin,
                                               const float* __restrict__ Dsv,
                                               const float* __restrict__ rmss,
                                               const float* __restrict__ x,
                                               float* __restrict__ out){
  const int task = blockIdx.x*4 + (threadIdx.x>>6);
  const int d = threadIdx.x & 63;
  const int b = task / NC, c = task % NC;
  float a0 = -expf(Alog[d*NS]);
  bool fast = true;
  #pragma unroll
  for (int n=1;n<NS;n++){
    float an = -expf(Alog[d*NS+n]);
    fast = fast && (fabsf(an - (float)(n+1)*a0) <= 1e-4f*(float)(n+1));
  }
  float h[12];
  {
    const float4* q = reinterpret_cast<const float4*>(hin + ((size_t)task*64 + d)*12);
    *reinterpret_cast<float4*>(&h[0]) = q[0];
    *reinterpret_cast<float4*>(&h[4]) = q[1];
    *reinterpret_cast<float4*>(&h[8]) = q[2];
  }
  const float Dd = Dsv[d];
  const float rsc = rmss[d];
  const int l0 = c*LC;
  #pragma unroll 1
  for (int g=0; g<LC/4; ++g){
    __half2 dv[4];
    float4 bq0[4], bq1[4], bq2[4];
    float xz[4];
    #pragma unroll
    for (int i=0;i<4;i++){
      size_t p = (size_t)b*LL + l0 + g*4 + i;
      dv[i] = duo[p*DD+d];
      const float4* q = reinterpret_cast<const float4*>(bch + p*24);
      bq0[i]=q[0]; bq1[i]=q[1]; bq2[i]=q[2];
      xz[i] = x[p*DD+d];
    }
    #pragma unroll
    for (int i=0;i<4;i++){
      size_t p = (size_t)b*LL + l0 + g*4 + i;
      float de = __low2float(dv[i]), uu = __high2float(dv[i]);
      float du = de*uu;
      __half2 h2[12];
      *reinterpret_cast<float4*>(&h2[0]) = bq0[i];
      *reinterpret_cast<float4*>(&h2[4]) = bq1[i];
      *reinterpret_cast<float4*>(&h2[8]) = bq2[i];
      float y = Dd*uu;
      if (fast){
        float r = __expf(a0*de);
        float dA = 1.f;
        #pragma unroll
        for (int n=0;n<NS;n++){
          dA *= r;
          float bn = (n&1) ? __high2float(h2[n>>1]) : __low2float(h2[n>>1]);
          float cn = (n&1) ? __high2float(h2[(12+n)>>1]) : __low2float(h2[(12+n)>>1]);
          h[n] = fmaf(dA, h[n], du*bn);
          y = fmaf(h[n], cn, y);
        }
      } else {
        #pragma unroll
        for (int n=0;n<NS;n++){
          float dA = __expf(-expf(Alog[d*NS+n])*de);
          float bn = (n&1) ? __high2float(h2[n>>1]) : __low2float(h2[n>>1]);
          float cn = (n&1) ? __high2float(h2[(12+n)>>1]) : __low2float(h2[(12+n)>>1]);
          h[n] = fmaf(dA, h[n], du*bn);
          y = fmaf(h[n], cn, y);
        }
      }
      float ss = y*y;
      #pragma unroll
      for (int m=1;m<64;m<<=1) ss += __shfl_xor(ss, m, 64);
      float yn = rsc * rsqrtf(ss*(1.f/64.f) + 1e-5f) * y;
      float z = xz[i];
      out[p*DD+d] = yn * (z * sigmoidf_(z));
    }
  }
}

extern "C" void kernel_launch(void* const* d_in, const int* in_sizes, int n_in,
                              void* d_out, int out_size, void* d_ws, size_t ws_size,
                              hipStream_t stream) {
  const float* x     = (const float*)d_in[0];
  const float* w     = (const float*)d_in[1];
  const float* gamma = (const float*)d_in[2];
  const float* beta  = (const float*)d_in[3];
  const float* xpw   = (const float*)d_in[4];
  const float* dtw   = (const float*)d_in[5];
  const float* dtb   = (const float*)d_in[6];
  const float* Alog  = (const float*)d_in[7];
  const float* Dsv   = (const float*)d_in[8];
  const float* rmss  = (const float*)d_in[9];
  float* out = (float*)d_out;

  float* f = (float*)d_ws;
  const size_t n_xld = (size_t)NB*LL*DD;       // 4,194,304
  __half*  xc  = (__half*)f;                   // conv out (fp16)
  __half2* duo = (__half2*)(f + n_xld);        // (b,l,d): half2(de,u)
  __half*  bch = (__half*)(f + n_xld + 2*n_xld); // (b,l,24) fp16
  float* chunkst = f + n_xld + 2*n_xld + (size_t)NB*LL*24;
  float* hin     = chunkst + (size_t)NB*NC*64*12;
  float* bn_acc  = hin + (size_t)NB*NC*64*12;      // 64 buckets x 128

  k_zero   <<<NBKT*128/256, 256, 0, stream>>>(bn_acc);
  k_conv   <<<NB*(LL/CONV_LT), 512, 0, stream>>>(x, w, xc, bn_acc);
  k_proj   <<<NB*(LL/PJ), 256, 0, stream>>>(xc, bn_acc, gamma, beta, xpw, dtw, dtb, Alog, duo, bch, chunkst);
  k_scanMid<<<NB*DD, 64, 0, stream>>>(chunkst, Alog, hin);
  k_scanB  <<<(NB*NC)/4, 256, 0, stream>>>(duo, bch, Alog, hin, Dsv, rmss, x, out);
}

// Round 21
// 83.584 us; speedup vs baseline: 1.0093x; 1.0093x over previous
//
#include <hip/hip_runtime.h>
#include <hip/hip_bf16.h>
#include <hip/hip_fp16.h>
#include <math.h>

#define NB 8
#define LL 8192
#define DD 64
#define NS 11
#define NR 4
#define NC 512        // chunks
#define LC (LL/NC)    // 16 positions per chunk
#define CONV_LT 128
#define KW 63
#define PJ 64         // proj tile = 4 chunks
#define NBKT 64       // BN atomic buckets
#define UH 72         // half stride for ulh rows
#define WS 72         // LDS row stride for wsh2 (f32)

__device__ __forceinline__ float sigmoidf_(float v){ return 1.f/(1.f+__expf(-v)); }
__device__ __forceinline__ float rnd16(float v){ return __half2float(__float2half_rn(v)); }

// ---------------- K0: zero the BN accumulator ----------------
__global__ void k_zero(float* __restrict__ p){
  p[blockIdx.x*256 + threadIdx.x] = 0.f;
}

// ---------------- K1: depthwise conv + BN partials + fp16 gate precompute ----------
__global__ __launch_bounds__(512,4) void k_conv(const float* __restrict__ x,
                                              const float* __restrict__ w,
                                              __half* __restrict__ xc,
                                              __half* __restrict__ gate,
                                              float* __restrict__ bn_acc){
  const int b  = blockIdx.x / (LL/CONV_LT);
  const int lt = blockIdx.x % (LL/CONV_LT);
  const int l0 = lt*CONV_LT;
  __shared__ float xt[(CONV_LT+62)*DD];   // 47.5 KB
  __shared__ float rs[512], rq[512];
  const int t = threadIdx.x;
  for (int i=t; i<(CONV_LT+62)*DD; i+=512){
    int lrel = i/DD, d = i%DD;
    int lg = l0 - 31 + lrel;
    xt[i] = (lg>=0 && lg<LL) ? x[((size_t)b*LL+lg)*DD + d] : 0.f;
  }
  __syncthreads();
  const int d = t & 63;
  const int base = (t >> 6) * 16;       // 8 waves x 16 positions
  float acc[16];
  #pragma unroll
  for (int j=0;j<16;j++) acc[j]=0.f;
  #pragma unroll 1
  for (int kb=0; kb<4; ++kb){
    float wv[16];
    #pragma unroll
    for (int kk=0;kk<16;kk++){
      int k = kb*16+kk;
      wv[kk] = (k<KW) ? w[d*KW+k] : 0.f;
    }
    float xw[31];
    #pragma unroll
    for (int i=0;i<31;i++) xw[i] = xt[(base+kb*16+i)*DD + d];
    #pragma unroll
    for (int j=0;j<16;j++){
      #pragma unroll
      for (int kk=0;kk<16;kk++){
        acc[j] = fmaf(wv[kk], xw[j+kk], acc[j]);
      }
    }
  }
  float lsum=0.f, lsq=0.f;
  #pragma unroll
  for (int j=0;j<16;j++){
    size_t p = (size_t)b*LL + l0+base+j;
    xc[p*DD + d] = __float2half_rn(acc[j]);
    float z = xt[(base+j+31)*DD + d];          // center tap = original x
    gate[p*DD + d] = __float2half_rn(z * sigmoidf_(z));
    lsum += acc[j]; lsq = fmaf(acc[j],acc[j],lsq);
  }
  rs[t]=lsum; rq[t]=lsq;
  __syncthreads();
  if (t<64){
    float s=0.f, q=0.f;
    #pragma unroll
    for (int g=0; g<8; ++g){ s += rs[t+64*g]; q += rq[t+64*g]; }
    const int bkt = (blockIdx.x & (NBKT-1))*128;
    atomicAdd(&bn_acc[bkt+t],    s);
    atomicAdd(&bn_acc[bkt+64+t], q);
  }
}

// ---------------- K2: BN+SiLU ; x_proj ; packed bch ; merged dt-proj + scan ---------
__global__ __launch_bounds__(256,5) void k_proj(const __half* __restrict__ xc,
                                              const float* __restrict__ bn_acc,
                                              const float* __restrict__ gamma,
                                              const float* __restrict__ beta,
                                              const float* __restrict__ xpw,
                                              const float* __restrict__ dtw,
                                              const float* __restrict__ dtb,
                                              const float* __restrict__ Alog,
                                              __half2* __restrict__ duo,
                                              __half* __restrict__ bch,
                                              float* __restrict__ chunkst){
  const int b  = blockIdx.x / (LL/PJ);
  const int lt = blockIdx.x % (LL/PJ);
  const int l0 = lt*PJ;
  __shared__ __align__(16) __half ulh[PJ*UH];   // 9.2 KB
  __shared__ float bcl[PJ][24];        // 6 KB
  __shared__ float wsh2[26*WS];        // 7.3 KB
  __shared__ float xd[PJ*NR];          // 1 KB
  __shared__ float dtwsh[64*NR];       // 1 KB
  __shared__ float bnred[2][4][64];    // 2 KB
  const int t = threadIdx.x;
  for (int i=t; i<26*64; i+=256){ int c=i>>6, dd=i&63; wsh2[c*WS+dd] = xpw[i]; }
  dtwsh[t] = dtw[t];
  if (t < 128){ bcl[t>>1][(t&1)?23:11] = 0.f; }   // zero pad slots for pack phase
  const int d = t & 63, wv = t >> 6;
  {
    float ms=0.f, qs=0.f;
    #pragma unroll
    for (int k=wv*16; k<wv*16+16; ++k){
      ms += bn_acc[k*128 + d];
      qs += bn_acc[k*128 + 64 + d];
    }
    bnred[0][wv][d]=ms; bnred[1][wv][d]=qs;
  }
  __syncthreads();
  float msum = bnred[0][0][d]+bnred[0][1][d]+bnred[0][2][d]+bnred[0][3][d];
  float qsum = bnred[1][0][d]+bnred[1][1][d]+bnred[1][2][d]+bnred[1][3][d];
  const float inv_n = 1.f/((float)NB*(float)LL);
  float mean = msum*inv_n;
  float var  = qsum*inv_n - mean*mean;
  float sc = gamma[d] * rsqrtf(var + 1e-5f);
  float sh = beta[d] - mean*sc;
  float uu[16];
  #pragma unroll
  for (int j=0;j<16;j++){
    int lr = wv*16 + j;
    float v = __half2float(xc[((size_t)b*LL + l0+lr)*DD + d]);
    v = fmaf(v, sc, sh);
    __half uh = __float2half_rn(v * sigmoidf_(v));
    uu[j] = __half2float(uh);
    ulh[lr*UH+d] = uh;
  }
  __syncthreads();
  // x_proj matvec: 2 cols x 4 pos x 8-dd blocking; u read as 8xfp16 per b128
  {
    const int cp  = t & 15;
    const int lrb = t >> 4;
    if (cp < 13){
      float acc0[4] = {0.f,0.f,0.f,0.f};
      float acc1[4] = {0.f,0.f,0.f,0.f};
      #pragma unroll 2
      for (int dd8=0; dd8<8; ++dd8){
        float4 w0a = *reinterpret_cast<const float4*>(&wsh2[(2*cp  )*WS + dd8*8]);
        float4 w0b = *reinterpret_cast<const float4*>(&wsh2[(2*cp  )*WS + dd8*8+4]);
        float4 w1a = *reinterpret_cast<const float4*>(&wsh2[(2*cp+1)*WS + dd8*8]);
        float4 w1b = *reinterpret_cast<const float4*>(&wsh2[(2*cp+1)*WS + dd8*8+4]);
        #pragma unroll
        for (int p=0;p<4;p++){
          float4 uvv = *reinterpret_cast<const float4*>(&ulh[(lrb*4+p)*UH + dd8*8]);
          const __half2* uh2 = reinterpret_cast<const __half2*>(&uvv);
          float2 f0 = __half22float2(uh2[0]);
          float2 f1 = __half22float2(uh2[1]);
          float2 f2 = __half22float2(uh2[2]);
          float2 f3 = __half22float2(uh2[3]);
          acc0[p] = fmaf(w0a.x,f0.x, fmaf(w0a.y,f0.y, fmaf(w0a.z,f1.x, fmaf(w0a.w,f1.y, acc0[p]))));
          acc0[p] = fmaf(w0b.x,f2.x, fmaf(w0b.y,f2.y, fmaf(w0b.z,f3.x, fmaf(w0b.w,f3.y, acc0[p]))));
          acc1[p] = fmaf(w1a.x,f0.x, fmaf(w1a.y,f0.y, fmaf(w1a.z,f1.x, fmaf(w1a.w,f1.y, acc1[p]))));
          acc1[p] = fmaf(w1b.x,f2.x, fmaf(w1b.y,f2.y, fmaf(w1b.z,f3.x, fmaf(w1b.w,f3.y, acc1[p]))));
        }
      }
      #pragma unroll
      for (int cc=0; cc<2; ++cc){
        int c = 2*cp+cc;
        #pragma unroll
        for (int p=0;p<4;p++){
          int lr = lrb*4+p;
          float v = cc ? acc1[p] : acc0[p];
          if (c < NR) xd[lr*NR+c] = v;
          else {
            int pos = c - NR;                       // B:0..10  C:11..21
            int slot = (pos < NS) ? pos : pos+1;    // pad slots 11 and 23
            bcl[lr][slot] = rnd16(v);               // fp16-consistent
          }
        }
      }
    }
  }
  __syncthreads();
  // coalesced bch pack: 64 pos x 24 half = 768 half2; thread t writes 3
  {
    __half2* dst = reinterpret_cast<__half2*>(bch + ((size_t)b*LL + l0)*24);
    #pragma unroll
    for (int r=0;r<3;r++){
      int j = t + 256*r;
      int pos = j / 12, sl = (j % 12)*2;
      dst[j] = __floats2half2_rn(bcl[pos][sl], bcl[pos][sl+1]);
    }
  }
  // merged dt-proj + softplus + duo(half2) store + chunk-local scan
  {
    const float bias = dtb[d];
    const float dw0 = dtwsh[d*NR+0], dw1 = dtwsh[d*NR+1],
                dw2 = dtwsh[d*NR+2], dw3 = dtwsh[d*NR+3];
    float a0 = -__expf(Alog[d*NS]);
    bool fast = true;
    #pragma unroll
    for (int n=1;n<NS;n++){
      float an = -__expf(Alog[d*NS+n]);
      fast = fast && (fabsf(an - (float)(n+1)*a0) <= 1e-4f*(float)(n+1));
    }
    const int task = b*NC + lt*4 + wv;
    float h[12];
    #pragma unroll
    for (int n=0;n<12;n++) h[n]=0.f;
    float dsum=0.f;
    #pragma unroll 4
    for (int l=0;l<LC;++l){
      int lr = wv*LC + l;
      float4 xv = *reinterpret_cast<const float4*>(&xd[lr*NR]);
      float s = fmaf(dw0,xv.x, fmaf(dw1,xv.y, fmaf(dw2,xv.z, fmaf(dw3,xv.w, bias))));
      float de = rnd16(fmaxf(s,0.f) + __logf(1.f + __expf(-fabsf(s))));
      float u_ = uu[l];
      float du = de*u_;
      dsum += de;
      duo[((size_t)b*LL + l0+lr)*DD + d] = __floats2half2_rn(de, u_);
      float bca[12];
      const float4* q = reinterpret_cast<const float4*>(&bcl[lr][0]);
      *reinterpret_cast<float4*>(&bca[0]) = q[0];
      *reinterpret_cast<float4*>(&bca[4]) = q[1];
      *reinterpret_cast<float4*>(&bca[8]) = q[2];
      if (fast){
        float r = __expf(a0*de);
        float dA = 1.f;
        #pragma unroll
        for (int n=0;n<NS;n++){
          dA *= r;
          h[n] = fmaf(dA, h[n], du*bca[n]);
        }
      } else {
        #pragma unroll
        for (int n=0;n<NS;n++){
          float dA = __expf(-__expf(Alog[d*NS+n])*de);
          h[n] = fmaf(dA, h[n], du*bca[n]);
        }
      }
    }
    h[11] = dsum;
    float4* o = reinterpret_cast<float4*>(chunkst + ((size_t)task*64 + d)*12);
    o[0] = *reinterpret_cast<float4*>(&h[0]);
    o[1] = *reinterpret_cast<float4*>(&h[4]);
    o[2] = *reinterpret_cast<float4*>(&h[8]);
  }
}

// ---------------- K4: cross-chunk propagation — recs in regs, hin fp16 -------------
__global__ __launch_bounds__(64) void k_scanMid(const float* __restrict__ chunkst,
                                                const float* __restrict__ Alog,
                                                __half* __restrict__ hin){
  const int wid  = blockIdx.x;
  const int lane = threadIdx.x & 63;
  const int b = wid >> 6, d = wid & 63;
  const int c0 = lane*8;
  const size_t recbase = (((size_t)b*NC + c0)*64 + d)*12;
  float rec[8][12];
  #pragma unroll
  for (int j=0;j<8;j++){
    const float4* q = reinterpret_cast<const float4*>(chunkst + recbase + (size_t)j*768);
    *reinterpret_cast<float4*>(&rec[j][0]) = q[0];
    *reinterpret_cast<float4*>(&rec[j][4]) = q[1];
    *reinterpret_cast<float4*>(&rec[j][8]) = q[2];
  }
  float aAll[NS];
  #pragma unroll
  for (int n=0;n<NS;n++) aAll[n] = -expf(Alog[d*NS+n]);
  bool fast = true;
  #pragma unroll
  for (int n=1;n<NS;n++)
    fast = fast && (fabsf(aAll[n] - (float)(n+1)*aAll[0]) <= 1e-4f*(float)(n+1));
  float Aa[NS], Bb[NS];
  #pragma unroll
  for (int n=0;n<NS;n++){ Aa[n]=1.f; Bb[n]=0.f; }
  #pragma unroll
  for (int j=0;j<8;j++){
    float ds = rec[j][11];
    if (fast){
      float r = __expf(aAll[0]*ds);
      float dA = 1.f;
      #pragma unroll
      for (int n=0;n<NS;n++){
        dA *= r;
        Bb[n] = fmaf(dA, Bb[n], rec[j][n]);
        Aa[n] *= dA;
      }
    } else {
      #pragma unroll
      for (int n=0;n<NS;n++){
        float dA = __expf(aAll[n]*ds);
        Bb[n] = fmaf(dA, Bb[n], rec[j][n]);
        Aa[n] *= dA;
      }
    }
  }
  #pragma unroll
  for (int n=0;n<NS;n++){
    float A = Aa[n], Bv = Bb[n];
    #pragma unroll
    for (int off=1; off<64; off<<=1){
      float Ap=__shfl_up(A,off,64), Bp=__shfl_up(Bv,off,64);
      if (lane>=off){ Bv = fmaf(A,Bp,Bv); A*=Ap; }
    }
    float hs = __shfl_up(Bv,1,64);
    Bb[n] = (lane==0) ? 0.f : hs;
  }
  #pragma unroll
  for (int j=0;j<8;j++){
    float ds = rec[j][11];
    float outv[12];
    if (fast){
      float r = __expf(aAll[0]*ds);
      float dA = 1.f;
      #pragma unroll
      for (int n=0;n<NS;n++){
        outv[n] = Bb[n];
        dA *= r;
        Bb[n] = fmaf(dA, Bb[n], rec[j][n]);
      }
    } else {
      #pragma unroll
      for (int n=0;n<NS;n++){
        outv[n] = Bb[n];
        float dA = __expf(aAll[n]*ds);
        Bb[n] = fmaf(dA, Bb[n], rec[j][n]);
      }
    }
    __half2 oh[8];
    oh[0]=__floats2half2_rn(outv[0],outv[1]);
    oh[1]=__floats2half2_rn(outv[2],outv[3]);
    oh[2]=__floats2half2_rn(outv[4],outv[5]);
    oh[3]=__floats2half2_rn(outv[6],outv[7]);
    oh[4]=__floats2half2_rn(outv[8],outv[9]);
    oh[5]=__floats2half2_rn(outv[10],0.f);
    oh[6]=__floats2half2_rn(0.f,0.f);
    oh[7]=oh[6];
    float4* o = reinterpret_cast<float4*>(hin + (((size_t)b*NC + c0+j)*64 + d)*16);
    o[0] = *reinterpret_cast<float4*>(&oh[0]);
    o[1] = *reinterpret_cast<float4*>(&oh[4]);
  }
}

// ---------------- K5: replay scan, batch-4 loads, RMSNorm, precomputed gate --------
__global__ __launch_bounds__(256,4) void k_scanB(const __half2* __restrict__ duo,
                                               const __half* __restrict__ bch,
                                               const float* __restrict__ Alog,
                                               const __half* __restrict__ hin,
                                               const float* __restrict__ Dsv,
                                               const float* __restrict__ rmss,
                                               const __half* __restrict__ gate,
                                               float* __restrict__ out){
  const int task = blockIdx.x*4 + (threadIdx.x>>6);
  const int d = threadIdx.x & 63;
  const int b = task / NC, c = task % NC;
  float a0 = -expf(Alog[d*NS]);
  bool fast = true;
  #pragma unroll
  for (int n=1;n<NS;n++){
    float an = -expf(Alog[d*NS+n]);
    fast = fast && (fabsf(an - (float)(n+1)*a0) <= 1e-4f*(float)(n+1));
  }
  float h[12];
  {
    const float4* q = reinterpret_cast<const float4*>(hin + ((size_t)task*64 + d)*16);
    float4 r0 = q[0], r1 = q[1];
    __half2 hh[8];
    *reinterpret_cast<float4*>(&hh[0]) = r0;
    *reinterpret_cast<float4*>(&hh[4]) = r1;
    h[0]=__low2float(hh[0]);  h[1]=__high2float(hh[0]);
    h[2]=__low2float(hh[1]);  h[3]=__high2float(hh[1]);
    h[4]=__low2float(hh[2]);  h[5]=__high2float(hh[2]);
    h[6]=__low2float(hh[3]);  h[7]=__high2float(hh[3]);
    h[8]=__low2float(hh[4]);  h[9]=__high2float(hh[4]);
    h[10]=__low2float(hh[5]); h[11]=0.f;
  }
  const float Dd = Dsv[d];
  const float rsc = rmss[d];
  const int l0 = c*LC;
  #pragma unroll 1
  for (int g=0; g<LC/4; ++g){
    __half2 dv[4];
    float4 bq0[4], bq1[4], bq2[4];
    __half gz[4];
    #pragma unroll
    for (int i=0;i<4;i++){
      size_t p = (size_t)b*LL + l0 + g*4 + i;
      dv[i] = duo[p*DD+d];
      const float4* q = reinterpret_cast<const float4*>(bch + p*24);
      bq0[i]=q[0]; bq1[i]=q[1]; bq2[i]=q[2];
      gz[i] = gate[p*DD+d];
    }
    #pragma unroll
    for (int i=0;i<4;i++){
      size_t p = (size_t)b*LL + l0 + g*4 + i;
      float de = __low2float(dv[i]), uu = __high2float(dv[i]);
      float du = de*uu;
      __half2 h2[12];
      *reinterpret_cast<float4*>(&h2[0]) = bq0[i];
      *reinterpret_cast<float4*>(&h2[4]) = bq1[i];
      *reinterpret_cast<float4*>(&h2[8]) = bq2[i];
      float y = Dd*uu;
      if (fast){
        float r = __expf(a0*de);
        float dA = 1.f;
        #pragma unroll
        for (int n=0;n<NS;n++){
          dA *= r;
          float bn = (n&1) ? __high2float(h2[n>>1]) : __low2float(h2[n>>1]);
          float cn = (n&1) ? __high2float(h2[(12+n)>>1]) : __low2float(h2[(12+n)>>1]);
          h[n] = fmaf(dA, h[n], du*bn);
          y = fmaf(h[n], cn, y);
        }
      } else {
        #pragma unroll
        for (int n=0;n<NS;n++){
          float dA = __expf(-expf(Alog[d*NS+n])*de);
          float bn = (n&1) ? __high2float(h2[n>>1]) : __low2float(h2[n>>1]);
          float cn = (n&1) ? __high2float(h2[(12+n)>>1]) : __low2float(h2[(12+n)>>1]);
          h[n] = fmaf(dA, h[n], du*bn);
          y = fmaf(h[n], cn, y);
        }
      }
      float ss = y*y;
      #pragma unroll
      for (int m=1;m<64;m<<=1) ss += __shfl_xor(ss, m, 64);
      float yn = rsc * rsqrtf(ss*(1.f/64.f) + 1e-5f) * y;
      out[p*DD+d] = yn * __half2float(gz[i]);
    }
  }
}

extern "C" void kernel_launch(void* const* d_in, const int* in_sizes, int n_in,
                              void* d_out, int out_size, void* d_ws, size_t ws_size,
                              hipStream_t stream) {
  const float* x     = (const float*)d_in[0];
  const float* w     = (const float*)d_in[1];
  const float* gamma = (const float*)d_in[2];
  const float* beta  = (const float*)d_in[3];
  const float* xpw   = (const float*)d_in[4];
  const float* dtw   = (const float*)d_in[5];
  const float* dtb   = (const float*)d_in[6];
  const float* Alog  = (const float*)d_in[7];
  const float* Dsv   = (const float*)d_in[8];
  const float* rmss  = (const float*)d_in[9];
  float* out = (float*)d_out;

  float* f = (float*)d_ws;
  const size_t n_xld = (size_t)NB*LL*DD;       // 4,194,304
  __half*  xc   = (__half*)f;                  // [0, n_xld) halfs
  __half*  gate = xc + n_xld;                  // [n_xld, 2*n_xld) halfs == f[.., n_xld)
  __half2* duo  = (__half2*)(f + n_xld);       // n_xld half2 = [n_xld, 2n_xld) floats
  __half*  bch  = (__half*)(f + 2*n_xld);      // NB*LL*24 halfs
  float* chunkst = f + 2*n_xld + (size_t)NB*LL*24/2 + 1024;  // f32 (b,c,d,12)
  __half* hin   = (__half*)(chunkst + (size_t)NB*NC*64*12);  // 16-half records
  float* bn_acc = chunkst + (size_t)NB*NC*64*12 + (size_t)NB*NC*64*8;

  k_zero   <<<NBKT*128/256, 256, 0, stream>>>(bn_acc);
  k_conv   <<<NB*(LL/CONV_LT), 512, 0, stream>>>(x, w, xc, gate, bn_acc);
  k_proj   <<<NB*(LL/PJ), 256, 0, stream>>>(xc, bn_acc, gamma, beta, xpw, dtw, dtb, Alog, duo, bch, chunkst);
  k_scanMid<<<NB*DD, 64, 0, stream>>>(chunkst, Alog, hin);
  k_scanB  <<<(NB*NC)/4, 256, 0, stream>>>(duo, bch, Alog, hin, Dsv, rmss, gate, out);
}

// Round 22
// 80.851 us; speedup vs baseline: 1.0434x; 1.0338x over previous
//
#include <hip/hip_runtime.h>
#include <hip/hip_bf16.h>
#include <hip/hip_fp16.h>
#include <math.h>

#define NB 8
#define LL 8192
#define DD 64
#define NS 11
#define NR 4
#define NC 512        // chunks
#define LC (LL/NC)    // 16 positions per chunk
#define CONV_LT 128
#define KW 63
#define PJ 64         // proj tile = 4 chunks
#define NBKT 64       // BN atomic buckets
#define UH 72         // half stride for ulh rows
#define WH 72         // half stride for wshh rows

typedef _Float16 h2v __attribute__((ext_vector_type(2)));

__device__ __forceinline__ float sigmoidf_(float v){ return 1.f/(1.f+__expf(-v)); }
__device__ __forceinline__ float rnd16(float v){ return __half2float(__float2half_rn(v)); }

// ---------------- K0: zero the BN accumulator ----------------
__global__ void k_zero(float* __restrict__ p){
  p[blockIdx.x*256 + threadIdx.x] = 0.f;
}

// ---------------- K1: depthwise conv + BN partials + fp16 gate precompute ----------
__global__ __launch_bounds__(512,4) void k_conv(const float* __restrict__ x,
                                              const float* __restrict__ w,
                                              __half* __restrict__ xc,
                                              __half* __restrict__ gate,
                                              float* __restrict__ bn_acc){
  const int b  = blockIdx.x / (LL/CONV_LT);
  const int lt = blockIdx.x % (LL/CONV_LT);
  const int l0 = lt*CONV_LT;
  __shared__ float xt[(CONV_LT+62)*DD];   // 47.5 KB
  __shared__ float rs[512], rq[512];
  const int t = threadIdx.x;
  for (int i=t; i<(CONV_LT+62)*DD; i+=512){
    int lrel = i/DD, d = i%DD;
    int lg = l0 - 31 + lrel;
    xt[i] = (lg>=0 && lg<LL) ? x[((size_t)b*LL+lg)*DD + d] : 0.f;
  }
  __syncthreads();
  const int d = t & 63;
  const int base = (t >> 6) * 16;       // 8 waves x 16 positions
  float acc[16];
  #pragma unroll
  for (int j=0;j<16;j++) acc[j]=0.f;
  #pragma unroll 1
  for (int kb=0; kb<4; ++kb){
    float wv[16];
    #pragma unroll
    for (int kk=0;kk<16;kk++){
      int k = kb*16+kk;
      wv[kk] = (k<KW) ? w[d*KW+k] : 0.f;
    }
    float xw[31];
    #pragma unroll
    for (int i=0;i<31;i++) xw[i] = xt[(base+kb*16+i)*DD + d];
    #pragma unroll
    for (int j=0;j<16;j++){
      #pragma unroll
      for (int kk=0;kk<16;kk++){
        acc[j] = fmaf(wv[kk], xw[j+kk], acc[j]);
      }
    }
  }
  float lsum=0.f, lsq=0.f;
  #pragma unroll
  for (int j=0;j<16;j++){
    size_t p = (size_t)b*LL + l0+base+j;
    xc[p*DD + d] = __float2half_rn(acc[j]);
    float z = xt[(base+j+31)*DD + d];          // center tap = original x
    gate[p*DD + d] = __float2half_rn(z * sigmoidf_(z));
    lsum += acc[j]; lsq = fmaf(acc[j],acc[j],lsq);
  }
  rs[t]=lsum; rq[t]=lsq;
  __syncthreads();
  if (t<64){
    float s=0.f, q=0.f;
    #pragma unroll
    for (int g=0; g<8; ++g){ s += rs[t+64*g]; q += rq[t+64*g]; }
    const int bkt = (blockIdx.x & (NBKT-1))*128;
    atomicAdd(&bn_acc[bkt+t],    s);
    atomicAdd(&bn_acc[bkt+64+t], q);
  }
}

// ---------------- K2: BN+SiLU ; fdot2 x_proj ; packed bch ; merged dt-proj + scan ---
__global__ __launch_bounds__(256,5) void k_proj(const __half* __restrict__ xc,
                                              const float* __restrict__ bn_acc,
                                              const float* __restrict__ gamma,
                                              const float* __restrict__ beta,
                                              const float* __restrict__ xpw,
                                              const float* __restrict__ dtw,
                                              const float* __restrict__ dtb,
                                              const float* __restrict__ Alog,
                                              __half2* __restrict__ duo,
                                              __half* __restrict__ bch,
                                              float* __restrict__ chunkst){
  const int b  = blockIdx.x / (LL/PJ);
  const int lt = blockIdx.x % (LL/PJ);
  const int l0 = lt*PJ;
  __shared__ __align__(16) _Float16 ulh[PJ*UH];   // 9.2 KB (u, fp16-exact)
  __shared__ __align__(16) _Float16 wshh[26*WH];  // 3.7 KB (W, fp16)
  __shared__ float bcl[PJ][24];        // 6 KB
  __shared__ float xd[PJ*NR];          // 1 KB
  __shared__ float dtwsh[64*NR];       // 1 KB
  __shared__ float bnred[2][4][64];    // 2 KB
  const int t = threadIdx.x;
  for (int i=t; i<26*64; i+=256){ int c=i>>6, dd=i&63; wshh[c*WH+dd] = (_Float16)xpw[i]; }
  dtwsh[t] = dtw[t];
  if (t < 128){ bcl[t>>1][(t&1)?23:11] = 0.f; }   // zero pad slots for pack phase
  const int d = t & 63, wv = t >> 6;
  {
    float ms=0.f, qs=0.f;
    #pragma unroll
    for (int k=wv*16; k<wv*16+16; ++k){
      ms += bn_acc[k*128 + d];
      qs += bn_acc[k*128 + 64 + d];
    }
    bnred[0][wv][d]=ms; bnred[1][wv][d]=qs;
  }
  __syncthreads();
  float msum = bnred[0][0][d]+bnred[0][1][d]+bnred[0][2][d]+bnred[0][3][d];
  float qsum = bnred[1][0][d]+bnred[1][1][d]+bnred[1][2][d]+bnred[1][3][d];
  const float inv_n = 1.f/((float)NB*(float)LL);
  float mean = msum*inv_n;
  float var  = qsum*inv_n - mean*mean;
  float sc = gamma[d] * rsqrtf(var + 1e-5f);
  float sh = beta[d] - mean*sc;
  float uu[16];
  #pragma unroll
  for (int j=0;j<16;j++){
    int lr = wv*16 + j;
    float v = __half2float(xc[((size_t)b*LL + l0+lr)*DD + d]);
    v = fmaf(v, sc, sh);
    _Float16 uh = (_Float16)(v * sigmoidf_(v));
    uu[j] = (float)uh;                 // fp16-consistent with scanB
    ulh[lr*UH+d] = uh;
  }
  __syncthreads();
  // x_proj matvec: 2 cols x 4 pos; v_dot2_f32_f16 over half pairs (no cvts)
  {
    const int cp  = t & 15;
    const int lrb = t >> 4;
    if (cp < 13){
      float acc0[4] = {0.f,0.f,0.f,0.f};
      float acc1[4] = {0.f,0.f,0.f,0.f};
      #pragma unroll 2
      for (int dd8=0; dd8<8; ++dd8){
        float4 w0v = *reinterpret_cast<const float4*>(&wshh[(2*cp  )*WH + dd8*8]);
        float4 w1v = *reinterpret_cast<const float4*>(&wshh[(2*cp+1)*WH + dd8*8]);
        const h2v* w0 = reinterpret_cast<const h2v*>(&w0v);
        const h2v* w1 = reinterpret_cast<const h2v*>(&w1v);
        #pragma unroll
        for (int p=0;p<4;p++){
          float4 uvv = *reinterpret_cast<const float4*>(&ulh[(lrb*4+p)*UH + dd8*8]);
          const h2v* up = reinterpret_cast<const h2v*>(&uvv);
#if __has_builtin(__builtin_amdgcn_fdot2)
          acc0[p] = __builtin_amdgcn_fdot2(w0[0], up[0], acc0[p], false);
          acc0[p] = __builtin_amdgcn_fdot2(w0[1], up[1], acc0[p], false);
          acc0[p] = __builtin_amdgcn_fdot2(w0[2], up[2], acc0[p], false);
          acc0[p] = __builtin_amdgcn_fdot2(w0[3], up[3], acc0[p], false);
          acc1[p] = __builtin_amdgcn_fdot2(w1[0], up[0], acc1[p], false);
          acc1[p] = __builtin_amdgcn_fdot2(w1[1], up[1], acc1[p], false);
          acc1[p] = __builtin_amdgcn_fdot2(w1[2], up[2], acc1[p], false);
          acc1[p] = __builtin_amdgcn_fdot2(w1[3], up[3], acc1[p], false);
#else
          #pragma unroll
          for (int q2=0;q2<4;q2++){
            acc0[p] += (float)w0[q2][0]*(float)up[q2][0] + (float)w0[q2][1]*(float)up[q2][1];
            acc1[p] += (float)w1[q2][0]*(float)up[q2][0] + (float)w1[q2][1]*(float)up[q2][1];
          }
#endif
        }
      }
      #pragma unroll
      for (int cc=0; cc<2; ++cc){
        int c = 2*cp+cc;
        #pragma unroll
        for (int p=0;p<4;p++){
          int lr = lrb*4+p;
          float v = cc ? acc1[p] : acc0[p];
          if (c < NR) xd[lr*NR+c] = v;
          else {
            int pos = c - NR;                       // B:0..10  C:11..21
            int slot = (pos < NS) ? pos : pos+1;    // pad slots 11 and 23
            bcl[lr][slot] = rnd16(v);               // fp16-consistent
          }
        }
      }
    }
  }
  __syncthreads();
  // coalesced bch pack: 64 pos x 24 half = 768 half2; thread t writes 3
  {
    __half2* dst = reinterpret_cast<__half2*>(bch + ((size_t)b*LL + l0)*24);
    #pragma unroll
    for (int r=0;r<3;r++){
      int j = t + 256*r;
      int pos = j / 12, sl = (j % 12)*2;
      dst[j] = __floats2half2_rn(bcl[pos][sl], bcl[pos][sl+1]);
    }
  }
  // merged dt-proj + softplus + duo(half2) store + chunk-local scan
  {
    const float bias = dtb[d];
    const float dw0 = dtwsh[d*NR+0], dw1 = dtwsh[d*NR+1],
                dw2 = dtwsh[d*NR+2], dw3 = dtwsh[d*NR+3];
    float a0 = -__expf(Alog[d*NS]);
    bool fast = true;
    #pragma unroll
    for (int n=1;n<NS;n++){
      float an = -__expf(Alog[d*NS+n]);
      fast = fast && (fabsf(an - (float)(n+1)*a0) <= 1e-4f*(float)(n+1));
    }
    const int task = b*NC + lt*4 + wv;
    float h[12];
    #pragma unroll
    for (int n=0;n<12;n++) h[n]=0.f;
    float dsum=0.f;
    #pragma unroll 4
    for (int l=0;l<LC;++l){
      int lr = wv*LC + l;
      float4 xv = *reinterpret_cast<const float4*>(&xd[lr*NR]);
      float s = fmaf(dw0,xv.x, fmaf(dw1,xv.y, fmaf(dw2,xv.z, fmaf(dw3,xv.w, bias))));
      float de = rnd16(fmaxf(s,0.f) + __logf(1.f + __expf(-fabsf(s))));
      float u_ = uu[l];
      float du = de*u_;
      dsum += de;
      duo[((size_t)b*LL + l0+lr)*DD + d] = __floats2half2_rn(de, u_);
      float bca[12];
      const float4* q = reinterpret_cast<const float4*>(&bcl[lr][0]);
      *reinterpret_cast<float4*>(&bca[0]) = q[0];
      *reinterpret_cast<float4*>(&bca[4]) = q[1];
      *reinterpret_cast<float4*>(&bca[8]) = q[2];
      if (fast){
        float r = __expf(a0*de);
        float dA = 1.f;
        #pragma unroll
        for (int n=0;n<NS;n++){
          dA *= r;
          h[n] = fmaf(dA, h[n], du*bca[n]);
        }
      } else {
        #pragma unroll
        for (int n=0;n<NS;n++){
          float dA = __expf(-__expf(Alog[d*NS+n])*de);
          h[n] = fmaf(dA, h[n], du*bca[n]);
        }
      }
    }
    h[11] = dsum;
    float4* o = reinterpret_cast<float4*>(chunkst + ((size_t)task*64 + d)*12);
    o[0] = *reinterpret_cast<float4*>(&h[0]);
    o[1] = *reinterpret_cast<float4*>(&h[4]);
    o[2] = *reinterpret_cast<float4*>(&h[8]);
  }
}

// ---------------- K4: cross-chunk propagation — recs in regs, hin fp16 -------------
__global__ __launch_bounds__(64) void k_scanMid(const float* __restrict__ chunkst,
                                                const float* __restrict__ Alog,
                                                __half* __restrict__ hin){
  const int wid  = blockIdx.x;
  const int lane = threadIdx.x & 63;
  const int b = wid >> 6, d = wid & 63;
  const int c0 = lane*8;
  const size_t recbase = (((size_t)b*NC + c0)*64 + d)*12;
  float rec[8][12];
  #pragma unroll
  for (int j=0;j<8;j++){
    const float4* q = reinterpret_cast<const float4*>(chunkst + recbase + (size_t)j*768);
    *reinterpret_cast<float4*>(&rec[j][0]) = q[0];
    *reinterpret_cast<float4*>(&rec[j][4]) = q[1];
    *reinterpret_cast<float4*>(&rec[j][8]) = q[2];
  }
  float aAll[NS];
  #pragma unroll
  for (int n=0;n<NS;n++) aAll[n] = -expf(Alog[d*NS+n]);
  bool fast = true;
  #pragma unroll
  for (int n=1;n<NS;n++)
    fast = fast && (fabsf(aAll[n] - (float)(n+1)*aAll[0]) <= 1e-4f*(float)(n+1));
  float Aa[NS], Bb[NS];
  #pragma unroll
  for (int n=0;n<NS;n++){ Aa[n]=1.f; Bb[n]=0.f; }
  #pragma unroll
  for (int j=0;j<8;j++){
    float ds = rec[j][11];
    if (fast){
      float r = __expf(aAll[0]*ds);
      float dA = 1.f;
      #pragma unroll
      for (int n=0;n<NS;n++){
        dA *= r;
        Bb[n] = fmaf(dA, Bb[n], rec[j][n]);
        Aa[n] *= dA;
      }
    } else {
      #pragma unroll
      for (int n=0;n<NS;n++){
        float dA = __expf(aAll[n]*ds);
        Bb[n] = fmaf(dA, Bb[n], rec[j][n]);
        Aa[n] *= dA;
      }
    }
  }
  #pragma unroll
  for (int n=0;n<NS;n++){
    float A = Aa[n], Bv = Bb[n];
    #pragma unroll
    for (int off=1; off<64; off<<=1){
      float Ap=__shfl_up(A,off,64), Bp=__shfl_up(Bv,off,64);
      if (lane>=off){ Bv = fmaf(A,Bp,Bv); A*=Ap; }
    }
    float hs = __shfl_up(Bv,1,64);
    Bb[n] = (lane==0) ? 0.f : hs;
  }
  #pragma unroll
  for (int j=0;j<8;j++){
    float ds = rec[j][11];
    float outv[12];
    if (fast){
      float r = __expf(aAll[0]*ds);
      float dA = 1.f;
      #pragma unroll
      for (int n=0;n<NS;n++){
        outv[n] = Bb[n];
        dA *= r;
        Bb[n] = fmaf(dA, Bb[n], rec[j][n]);
      }
    } else {
      #pragma unroll
      for (int n=0;n<NS;n++){
        outv[n] = Bb[n];
        float dA = __expf(aAll[n]*ds);
        Bb[n] = fmaf(dA, Bb[n], rec[j][n]);
      }
    }
    __half2 oh[8];
    oh[0]=__floats2half2_rn(outv[0],outv[1]);
    oh[1]=__floats2half2_rn(outv[2],outv[3]);
    oh[2]=__floats2half2_rn(outv[4],outv[5]);
    oh[3]=__floats2half2_rn(outv[6],outv[7]);
    oh[4]=__floats2half2_rn(outv[8],outv[9]);
    oh[5]=__floats2half2_rn(outv[10],0.f);
    oh[6]=__floats2half2_rn(0.f,0.f);
    oh[7]=oh[6];
    float4* o = reinterpret_cast<float4*>(hin + (((size_t)b*NC + c0+j)*64 + d)*16);
    o[0] = *reinterpret_cast<float4*>(&oh[0]);
    o[1] = *reinterpret_cast<float4*>(&oh[4]);
  }
}

// ---------------- K5: replay scan, batch-4 loads, RMSNorm, precomputed gate --------
__global__ __launch_bounds__(256,4) void k_scanB(const __half2* __restrict__ duo,
                                               const __half* __restrict__ bch,
                                               const float* __restrict__ Alog,
                                               const __half* __restrict__ hin,
                                               const float* __restrict__ Dsv,
                                               const float* __restrict__ rmss,
                                               const __half* __restrict__ gate,
                                               float* __restrict__ out){
  const int task = blockIdx.x*4 + (threadIdx.x>>6);
  const int d = threadIdx.x & 63;
  const int b = task / NC, c = task % NC;
  float a0 = -expf(Alog[d*NS]);
  bool fast = true;
  #pragma unroll
  for (int n=1;n<NS;n++){
    float an = -expf(Alog[d*NS+n]);
    fast = fast && (fabsf(an - (float)(n+1)*a0) <= 1e-4f*(float)(n+1));
  }
  float h[12];
  {
    const float4* q = reinterpret_cast<const float4*>(hin + ((size_t)task*64 + d)*16);
    float4 r0 = q[0], r1 = q[1];
    __half2 hh[8];
    *reinterpret_cast<float4*>(&hh[0]) = r0;
    *reinterpret_cast<float4*>(&hh[4]) = r1;
    h[0]=__low2float(hh[0]);  h[1]=__high2float(hh[0]);
    h[2]=__low2float(hh[1]);  h[3]=__high2float(hh[1]);
    h[4]=__low2float(hh[2]);  h[5]=__high2float(hh[2]);
    h[6]=__low2float(hh[3]);  h[7]=__high2float(hh[3]);
    h[8]=__low2float(hh[4]);  h[9]=__high2float(hh[4]);
    h[10]=__low2float(hh[5]); h[11]=0.f;
  }
  const float Dd = Dsv[d];
  const float rsc = rmss[d];
  const int l0 = c*LC;
  #pragma unroll 1
  for (int g=0; g<LC/4; ++g){
    __half2 dv[4];
    float4 bq0[4], bq1[4], bq2[4];
    __half gz[4];
    #pragma unroll
    for (int i=0;i<4;i++){
      size_t p = (size_t)b*LL + l0 + g*4 + i;
      dv[i] = duo[p*DD+d];
      const float4* q = reinterpret_cast<const float4*>(bch + p*24);
      bq0[i]=q[0]; bq1[i]=q[1]; bq2[i]=q[2];
      gz[i] = gate[p*DD+d];
    }
    #pragma unroll
    for (int i=0;i<4;i++){
      size_t p = (size_t)b*LL + l0 + g*4 + i;
      float de = __low2float(dv[i]), uu = __high2float(dv[i]);
      float du = de*uu;
      __half2 h2[12];
      *reinterpret_cast<float4*>(&h2[0]) = bq0[i];
      *reinterpret_cast<float4*>(&h2[4]) = bq1[i];
      *reinterpret_cast<float4*>(&h2[8]) = bq2[i];
      float y = Dd*uu;
      if (fast){
        float r = __expf(a0*de);
        float dA = 1.f;
        #pragma unroll
        for (int n=0;n<NS;n++){
          dA *= r;
          float bn = (n&1) ? __high2float(h2[n>>1]) : __low2float(h2[n>>1]);
          float cn = (n&1) ? __high2float(h2[(12+n)>>1]) : __low2float(h2[(12+n)>>1]);
          h[n] = fmaf(dA, h[n], du*bn);
          y = fmaf(h[n], cn, y);
        }
      } else {
        #pragma unroll
        for (int n=0;n<NS;n++){
          float dA = __expf(-expf(Alog[d*NS+n])*de);
          float bn = (n&1) ? __high2float(h2[n>>1]) : __low2float(h2[n>>1]);
          float cn = (n&1) ? __high2float(h2[(12+n)>>1]) : __low2float(h2[(12+n)>>1]);
          h[n] = fmaf(dA, h[n], du*bn);
          y = fmaf(h[n], cn, y);
        }
      }
      float ss = y*y;
      #pragma unroll
      for (int m=1;m<64;m<<=1) ss += __shfl_xor(ss, m, 64);
      float yn = rsc * rsqrtf(ss*(1.f/64.f) + 1e-5f) * y;
      out[p*DD+d] = yn * __half2float(gz[i]);
    }
  }
}

extern "C" void kernel_launch(void* const* d_in, const int* in_sizes, int n_in,
                              void* d_out, int out_size, void* d_ws, size_t ws_size,
                              hipStream_t stream) {
  const float* x     = (const float*)d_in[0];
  const float* w     = (const float*)d_in[1];
  const float* gamma = (const float*)d_in[2];
  const float* beta  = (const float*)d_in[3];
  const float* xpw   = (const float*)d_in[4];
  const float* dtw   = (const float*)d_in[5];
  const float* dtb   = (const float*)d_in[6];
  const float* Alog  = (const float*)d_in[7];
  const float* Dsv   = (const float*)d_in[8];
  const float* rmss  = (const float*)d_in[9];
  float* out = (float*)d_out;

  float* f = (float*)d_ws;
  const size_t n_xld = (size_t)NB*LL*DD;       // 4,194,304
  __half*  xc   = (__half*)f;                  // [0, n_xld) halfs
  __half*  gate = xc + n_xld;                  // [n_xld, 2*n_xld) halfs
  __half2* duo  = (__half2*)(f + n_xld);       // n_xld half2
  __half*  bch  = (__half*)(f + 2*n_xld);      // NB*LL*24 halfs
  float* chunkst = f + 2*n_xld + (size_t)NB*LL*24/2 + 1024;  // f32 (b,c,d,12)
  __half* hin   = (__half*)(chunkst + (size_t)NB*NC*64*12);  // 16-half records
  float* bn_acc = chunkst + (size_t)NB*NC*64*12 + (size_t)NB*NC*64*8;

  k_zero   <<<NBKT*128/256, 256, 0, stream>>>(bn_acc);
  k_conv   <<<NB*(LL/CONV_LT), 512, 0, stream>>>(x, w, xc, gate, bn_acc);
  k_proj   <<<NB*(LL/PJ), 256, 0, stream>>>(xc, bn_acc, gamma, beta, xpw, dtw, dtb, Alog, duo, bch, chunkst);
  k_scanMid<<<NB*DD, 64, 0, stream>>>(chunkst, Alog, hin);
  k_scanB  <<<(NB*NC)/4, 256, 0, stream>>>(duo, bch, Alog, hin, Dsv, rmss, gate, out);
}

// Round 23
// 79.798 us; speedup vs baseline: 1.0571x; 1.0132x over previous
//
#include <hip/hip_runtime.h>
#include <hip/hip_bf16.h>
#include <hip/hip_fp16.h>
#include <math.h>

#define NB 8
#define LL 8192
#define DD 64
#define NS 11
#define NR 4
#define NC 512        // chunks
#define LC (LL/NC)    // 16 positions per chunk
#define CONV_LT 128
#define KW 63
#define PJ 64         // proj tile = 4 chunks
#define UH 72         // half stride for ulh rows
#define WH 72         // half stride for wshh rows
#define NCB (NB*(LL/CONV_LT))   // 512 conv blocks

typedef _Float16 h2v __attribute__((ext_vector_type(2)));

__device__ __forceinline__ float sigmoidf_(float v){ return 1.f/(1.f+__expf(-v)); }
__device__ __forceinline__ float rnd16(float v){ return __half2float(__float2half_rn(v)); }

// ---------------- K1: depthwise conv + non-atomic BN partials + fp16 gate ----------
__global__ __launch_bounds__(512,4) void k_conv(const float* __restrict__ x,
                                              const float* __restrict__ w,
                                              __half* __restrict__ xc,
                                              __half* __restrict__ gate,
                                              float* __restrict__ bn_part){
  const int b  = blockIdx.x / (LL/CONV_LT);
  const int lt = blockIdx.x % (LL/CONV_LT);
  const int l0 = lt*CONV_LT;
  __shared__ float xt[(CONV_LT+62)*DD];   // 47.5 KB
  __shared__ float rs[512], rq[512];
  const int t = threadIdx.x;
  for (int i=t; i<(CONV_LT+62)*DD; i+=512){
    int lrel = i/DD, d = i%DD;
    int lg = l0 - 31 + lrel;
    xt[i] = (lg>=0 && lg<LL) ? x[((size_t)b*LL+lg)*DD + d] : 0.f;
  }
  __syncthreads();
  const int d = t & 63;
  const int base = (t >> 6) * 16;       // 8 waves x 16 positions
  float acc[16];
  #pragma unroll
  for (int j=0;j<16;j++) acc[j]=0.f;
  #pragma unroll 1
  for (int kb=0; kb<4; ++kb){
    float wv[16];
    #pragma unroll
    for (int kk=0;kk<16;kk++){
      int k = kb*16+kk;
      wv[kk] = (k<KW) ? w[d*KW+k] : 0.f;
    }
    float xw[31];
    #pragma unroll
    for (int i=0;i<31;i++) xw[i] = xt[(base+kb*16+i)*DD + d];
    #pragma unroll
    for (int j=0;j<16;j++){
      #pragma unroll
      for (int kk=0;kk<16;kk++){
        acc[j] = fmaf(wv[kk], xw[j+kk], acc[j]);
      }
    }
  }
  float lsum=0.f, lsq=0.f;
  #pragma unroll
  for (int j=0;j<16;j++){
    size_t p = (size_t)b*LL + l0+base+j;
    xc[p*DD + d] = __float2half_rn(acc[j]);
    float z = xt[(base+j+31)*DD + d];          // center tap = original x
    gate[p*DD + d] = __float2half_rn(z * sigmoidf_(z));
    lsum += acc[j]; lsq = fmaf(acc[j],acc[j],lsq);
  }
  rs[t]=lsum; rq[t]=lsq;
  __syncthreads();
  if (t<64){
    float s=0.f, q=0.f;
    #pragma unroll
    for (int g=0; g<8; ++g){ s += rs[t+64*g]; q += rq[t+64*g]; }
    bn_part[(size_t)blockIdx.x*128 + t]      = s;
    bn_part[(size_t)blockIdx.x*128 + 64 + t] = q;
  }
}

// ---------------- K1b: reduce 512 BN partial slots -> per-channel (sc, sh) ---------
__global__ __launch_bounds__(512) void k_bnred(const float* __restrict__ bn_part,
                                               const float* __restrict__ gamma,
                                               const float* __restrict__ beta,
                                               float* __restrict__ bnp){
  __shared__ float red[2][8][64];
  const int t = threadIdx.x;
  const int d = t & 63, grp = t >> 6;       // 8 groups x 64 slots
  float s=0.f, q=0.f;
  #pragma unroll 8
  for (int k=grp*64; k<grp*64+64; ++k){
    s += bn_part[(size_t)k*128 + d];
    q += bn_part[(size_t)k*128 + 64 + d];
  }
  red[0][grp][d]=s; red[1][grp][d]=q;
  __syncthreads();
  if (t < 64){
    float ms=0.f, qs=0.f;
    #pragma unroll
    for (int g=0;g<8;g++){ ms += red[0][g][t]; qs += red[1][g][t]; }
    const float inv_n = 1.f/((float)NB*(float)LL);
    float mean = ms*inv_n;
    float var  = qs*inv_n - mean*mean;
    float sc = gamma[t] * rsqrtf(var + 1e-5f);
    bnp[t]    = sc;
    bnp[64+t] = beta[t] - mean*sc;
  }
}

// ---------------- K2: BN+SiLU ; fdot2 x_proj ; packed bch ; merged dt-proj + scan ---
__global__ __launch_bounds__(256,5) void k_proj(const __half* __restrict__ xc,
                                              const float* __restrict__ bnp,
                                              const float* __restrict__ xpw,
                                              const float* __restrict__ dtw,
                                              const float* __restrict__ dtb,
                                              const float* __restrict__ Alog,
                                              __half2* __restrict__ duo,
                                              __half* __restrict__ bch,
                                              float* __restrict__ chunkst){
  const int b  = blockIdx.x / (LL/PJ);
  const int lt = blockIdx.x % (LL/PJ);
  const int l0 = lt*PJ;
  __shared__ __align__(16) _Float16 ulh[PJ*UH];   // 9.2 KB
  __shared__ __align__(16) _Float16 wshh[26*WH];  // 3.7 KB
  __shared__ float bcl[PJ][24];        // 6 KB
  __shared__ float xd[PJ*NR];          // 1 KB
  __shared__ float dtwsh[64*NR];       // 1 KB
  const int t = threadIdx.x;
  for (int i=t; i<26*64; i+=256){ int c=i>>6, dd=i&63; wshh[c*WH+dd] = (_Float16)xpw[i]; }
  dtwsh[t] = dtw[t];
  if (t < 128){ bcl[t>>1][(t&1)?23:11] = 0.f; }   // zero pad slots for pack phase
  const int d = t & 63, wv = t >> 6;
  float sc = bnp[d], sh = bnp[64+d];
  float uu[16];
  #pragma unroll
  for (int j=0;j<16;j++){
    int lr = wv*16 + j;
    float v = __half2float(xc[((size_t)b*LL + l0+lr)*DD + d]);
    v = fmaf(v, sc, sh);
    _Float16 uh = (_Float16)(v * sigmoidf_(v));
    uu[j] = (float)uh;                 // fp16-consistent with scanB
    ulh[lr*UH+d] = uh;
  }
  __syncthreads();
  // x_proj matvec: 2 cols x 4 pos; v_dot2_f32_f16 over half pairs
  {
    const int cp  = t & 15;
    const int lrb = t >> 4;
    if (cp < 13){
      float acc0[4] = {0.f,0.f,0.f,0.f};
      float acc1[4] = {0.f,0.f,0.f,0.f};
      #pragma unroll 2
      for (int dd8=0; dd8<8; ++dd8){
        float4 w0v = *reinterpret_cast<const float4*>(&wshh[(2*cp  )*WH + dd8*8]);
        float4 w1v = *reinterpret_cast<const float4*>(&wshh[(2*cp+1)*WH + dd8*8]);
        const h2v* w0 = reinterpret_cast<const h2v*>(&w0v);
        const h2v* w1 = reinterpret_cast<const h2v*>(&w1v);
        #pragma unroll
        for (int p=0;p<4;p++){
          float4 uvv = *reinterpret_cast<const float4*>(&ulh[(lrb*4+p)*UH + dd8*8]);
          const h2v* up = reinterpret_cast<const h2v*>(&uvv);
#if __has_builtin(__builtin_amdgcn_fdot2)
          acc0[p] = __builtin_amdgcn_fdot2(w0[0], up[0], acc0[p], false);
          acc0[p] = __builtin_amdgcn_fdot2(w0[1], up[1], acc0[p], false);
          acc0[p] = __builtin_amdgcn_fdot2(w0[2], up[2], acc0[p], false);
          acc0[p] = __builtin_amdgcn_fdot2(w0[3], up[3], acc0[p], false);
          acc1[p] = __builtin_amdgcn_fdot2(w1[0], up[0], acc1[p], false);
          acc1[p] = __builtin_amdgcn_fdot2(w1[1], up[1], acc1[p], false);
          acc1[p] = __builtin_amdgcn_fdot2(w1[2], up[2], acc1[p], false);
          acc1[p] = __builtin_amdgcn_fdot2(w1[3], up[3], acc1[p], false);
#else
          #pragma unroll
          for (int q2=0;q2<4;q2++){
            acc0[p] += (float)w0[q2][0]*(float)up[q2][0] + (float)w0[q2][1]*(float)up[q2][1];
            acc1[p] += (float)w1[q2][0]*(float)up[q2][0] + (float)w1[q2][1]*(float)up[q2][1];
          }
#endif
        }
      }
      #pragma unroll
      for (int cc=0; cc<2; ++cc){
        int c = 2*cp+cc;
        #pragma unroll
        for (int p=0;p<4;p++){
          int lr = lrb*4+p;
          float v = cc ? acc1[p] : acc0[p];
          if (c < NR) xd[lr*NR+c] = v;
          else {
            int pos = c - NR;                       // B:0..10  C:11..21
            int slot = (pos < NS) ? pos : pos+1;    // pad slots 11 and 23
            bcl[lr][slot] = rnd16(v);               // fp16-consistent
          }
        }
      }
    }
  }
  __syncthreads();
  // coalesced bch pack: 64 pos x 24 half = 768 half2; thread t writes 3
  {
    __half2* dst = reinterpret_cast<__half2*>(bch + ((size_t)b*LL + l0)*24);
    #pragma unroll
    for (int r=0;r<3;r++){
      int j = t + 256*r;
      int pos = j / 12, sl = (j % 12)*2;
      dst[j] = __floats2half2_rn(bcl[pos][sl], bcl[pos][sl+1]);
    }
  }
  // merged dt-proj + softplus + duo(half2) store + chunk-local scan
  {
    const float bias = dtb[d];
    const float dw0 = dtwsh[d*NR+0], dw1 = dtwsh[d*NR+1],
                dw2 = dtwsh[d*NR+2], dw3 = dtwsh[d*NR+3];
    float a0 = -__expf(Alog[d*NS]);
    bool fast = true;
    #pragma unroll
    for (int n=1;n<NS;n++){
      float an = -__expf(Alog[d*NS+n]);
      fast = fast && (fabsf(an - (float)(n+1)*a0) <= 1e-4f*(float)(n+1));
    }
    const int task = b*NC + lt*4 + wv;
    float h[12];
    #pragma unroll
    for (int n=0;n<12;n++) h[n]=0.f;
    float dsum=0.f;
    #pragma unroll 4
    for (int l=0;l<LC;++l){
      int lr = wv*LC + l;
      float4 xv = *reinterpret_cast<const float4*>(&xd[lr*NR]);
      float s = fmaf(dw0,xv.x, fmaf(dw1,xv.y, fmaf(dw2,xv.z, fmaf(dw3,xv.w, bias))));
      float de = rnd16(fmaxf(s,0.f) + __logf(1.f + __expf(-fabsf(s))));
      float u_ = uu[l];
      float du = de*u_;
      dsum += de;
      duo[((size_t)b*LL + l0+lr)*DD + d] = __floats2half2_rn(de, u_);
      float bca[12];
      const float4* q = reinterpret_cast<const float4*>(&bcl[lr][0]);
      *reinterpret_cast<float4*>(&bca[0]) = q[0];
      *reinterpret_cast<float4*>(&bca[4]) = q[1];
      *reinterpret_cast<float4*>(&bca[8]) = q[2];
      if (fast){
        float r = __expf(a0*de);
        float dA = 1.f;
        #pragma unroll
        for (int n=0;n<NS;n++){
          dA *= r;
          h[n] = fmaf(dA, h[n], du*bca[n]);
        }
      } else {
        #pragma unroll
        for (int n=0;n<NS;n++){
          float dA = __expf(-__expf(Alog[d*NS+n])*de);
          h[n] = fmaf(dA, h[n], du*bca[n]);
        }
      }
    }
    h[11] = dsum;
    float4* o = reinterpret_cast<float4*>(chunkst + ((size_t)task*64 + d)*12);
    o[0] = *reinterpret_cast<float4*>(&h[0]);
    o[1] = *reinterpret_cast<float4*>(&h[4]);
    o[2] = *reinterpret_cast<float4*>(&h[8]);
  }
}

// ---------------- K4: cross-chunk propagation — 2 waves per (b,d), 4 chunks/lane ----
__global__ __launch_bounds__(128) void k_scanMid(const float* __restrict__ chunkst,
                                                 const float* __restrict__ Alog,
                                                 __half* __restrict__ hin){
  const int wid  = blockIdx.x;                 // 0..511 = b*64+d
  const int wave = threadIdx.x >> 6;           // 0..1
  const int lane = threadIdx.x & 63;
  const int b = wid >> 6, d = wid & 63;
  const int cbase = wave*256 + lane*4;
  __shared__ float wtot[2][12];                // wave0 totals (A,B) per n
  float rec[4][12];
  #pragma unroll
  for (int j=0;j<4;j++){
    const float4* q = reinterpret_cast<const float4*>(chunkst + (((size_t)b*NC + cbase+j)*64 + d)*12);
    *reinterpret_cast<float4*>(&rec[j][0]) = q[0];
    *reinterpret_cast<float4*>(&rec[j][4]) = q[1];
    *reinterpret_cast<float4*>(&rec[j][8]) = q[2];
  }
  float aAll[NS];
  #pragma unroll
  for (int n=0;n<NS;n++) aAll[n] = -expf(Alog[d*NS+n]);
  bool fast = true;
  #pragma unroll
  for (int n=1;n<NS;n++)
    fast = fast && (fabsf(aAll[n] - (float)(n+1)*aAll[0]) <= 1e-4f*(float)(n+1));
  // local affine compose over 4 chunks
  float Ai[NS], Bi[NS];
  #pragma unroll
  for (int n=0;n<NS;n++){ Ai[n]=1.f; Bi[n]=0.f; }
  #pragma unroll
  for (int j=0;j<4;j++){
    float ds = rec[j][11];
    if (fast){
      float r = __expf(aAll[0]*ds);
      float dA = 1.f;
      #pragma unroll
      for (int n=0;n<NS;n++){
        dA *= r;
        Bi[n] = fmaf(dA, Bi[n], rec[j][n]);
        Ai[n] *= dA;
      }
    } else {
      #pragma unroll
      for (int n=0;n<NS;n++){
        float dA = __expf(aAll[n]*ds);
        Bi[n] = fmaf(dA, Bi[n], rec[j][n]);
        Ai[n] *= dA;
      }
    }
  }
  // inclusive lane-scan per n
  #pragma unroll
  for (int n=0;n<NS;n++){
    float A = Ai[n], Bv = Bi[n];
    #pragma unroll
    for (int off=1; off<64; off<<=1){
      float Ap=__shfl_up(A,off,64), Bp=__shfl_up(Bv,off,64);
      if (lane>=off){ Bv = fmaf(A,Bp,Bv); A*=Ap; }
    }
    Ai[n]=A; Bi[n]=Bv;                         // inclusive prefix
  }
  if (wave==0 && lane==63){
    #pragma unroll
    for (int n=0;n<NS;n++){ wtot[0][n]=Ai[n]; wtot[1][n]=Bi[n]; }
  }
  __syncthreads();
  // exclusive prefix + cross-wave composition; h_start (global h0 = 0)
  float hst[NS];
  #pragma unroll
  for (int n=0;n<NS;n++){
    float Aex = __shfl_up(Ai[n],1,64);
    float Bex = __shfl_up(Bi[n],1,64);
    if (lane==0){ Aex=1.f; Bex=0.f; }
    if (wave==0) hst[n] = Bex;
    else         hst[n] = fmaf(Aex, wtot[1][n], Bex);
  }
  // replay 4 chunks writing fp16 hin records
  #pragma unroll
  for (int j=0;j<4;j++){
    float ds = rec[j][11];
    __half2 oh[8];
    oh[0]=__floats2half2_rn(hst[0],hst[1]);
    oh[1]=__floats2half2_rn(hst[2],hst[3]);
    oh[2]=__floats2half2_rn(hst[4],hst[5]);
    oh[3]=__floats2half2_rn(hst[6],hst[7]);
    oh[4]=__floats2half2_rn(hst[8],hst[9]);
    oh[5]=__floats2half2_rn(hst[10],0.f);
    oh[6]=__floats2half2_rn(0.f,0.f);
    oh[7]=oh[6];
    float4* o = reinterpret_cast<float4*>(hin + (((size_t)b*NC + cbase+j)*64 + d)*16);
    o[0] = *reinterpret_cast<float4*>(&oh[0]);
    o[1] = *reinterpret_cast<float4*>(&oh[4]);
    if (fast){
      float r = __expf(aAll[0]*ds);
      float dA = 1.f;
      #pragma unroll
      for (int n=0;n<NS;n++){
        dA *= r;
        hst[n] = fmaf(dA, hst[n], rec[j][n]);
      }
    } else {
      #pragma unroll
      for (int n=0;n<NS;n++){
        float dA = __expf(aAll[n]*ds);
        hst[n] = fmaf(dA, hst[n], rec[j][n]);
      }
    }
  }
}

// ---------------- K5: replay scan, batch-4 loads, RMSNorm, precomputed gate --------
__global__ __launch_bounds__(256,4) void k_scanB(const __half2* __restrict__ duo,
                                               const __half* __restrict__ bch,
                                               const float* __restrict__ Alog,
                                               const __half* __restrict__ hin,
                                               const float* __restrict__ Dsv,
                                               const float* __restrict__ rmss,
                                               const __half* __restrict__ gate,
                                               float* __restrict__ out){
  const int task = blockIdx.x*4 + (threadIdx.x>>6);
  const int d = threadIdx.x & 63;
  const int b = task / NC, c = task % NC;
  float a0 = -expf(Alog[d*NS]);
  bool fast = true;
  #pragma unroll
  for (int n=1;n<NS;n++){
    float an = -expf(Alog[d*NS+n]);
    fast = fast && (fabsf(an - (float)(n+1)*a0) <= 1e-4f*(float)(n+1));
  }
  float h[12];
  {
    const float4* q = reinterpret_cast<const float4*>(hin + ((size_t)task*64 + d)*16);
    float4 r0 = q[0], r1 = q[1];
    __half2 hh[8];
    *reinterpret_cast<float4*>(&hh[0]) = r0;
    *reinterpret_cast<float4*>(&hh[4]) = r1;
    h[0]=__low2float(hh[0]);  h[1]=__high2float(hh[0]);
    h[2]=__low2float(hh[1]);  h[3]=__high2float(hh[1]);
    h[4]=__low2float(hh[2]);  h[5]=__high2float(hh[2]);
    h[6]=__low2float(hh[3]);  h[7]=__high2float(hh[3]);
    h[8]=__low2float(hh[4]);  h[9]=__high2float(hh[4]);
    h[10]=__low2float(hh[5]); h[11]=0.f;
  }
  const float Dd = Dsv[d];
  const float rsc = rmss[d];
  const int l0 = c*LC;
  #pragma unroll 1
  for (int g=0; g<LC/4; ++g){
    __half2 dv[4];
    float4 bq0[4], bq1[4], bq2[4];
    __half gz[4];
    #pragma unroll
    for (int i=0;i<4;i++){
      size_t p = (size_t)b*LL + l0 + g*4 + i;
      dv[i] = duo[p*DD+d];
      const float4* q = reinterpret_cast<const float4*>(bch + p*24);
      bq0[i]=q[0]; bq1[i]=q[1]; bq2[i]=q[2];
      gz[i] = gate[p*DD+d];
    }
    #pragma unroll
    for (int i=0;i<4;i++){
      size_t p = (size_t)b*LL + l0 + g*4 + i;
      float de = __low2float(dv[i]), uu = __high2float(dv[i]);
      float du = de*uu;
      __half2 h2[12];
      *reinterpret_cast<float4*>(&h2[0]) = bq0[i];
      *reinterpret_cast<float4*>(&h2[4]) = bq1[i];
      *reinterpret_cast<float4*>(&h2[8]) = bq2[i];
      float y = Dd*uu;
      if (fast){
        float r = __expf(a0*de);
        float dA = 1.f;
        #pragma unroll
        for (int n=0;n<NS;n++){
          dA *= r;
          float bn = (n&1) ? __high2float(h2[n>>1]) : __low2float(h2[n>>1]);
          float cn = (n&1) ? __high2float(h2[(12+n)>>1]) : __low2float(h2[(12+n)>>1]);
          h[n] = fmaf(dA, h[n], du*bn);
          y = fmaf(h[n], cn, y);
        }
      } else {
        #pragma unroll
        for (int n=0;n<NS;n++){
          float dA = __expf(-expf(Alog[d*NS+n])*de);
          float bn = (n&1) ? __high2float(h2[n>>1]) : __low2float(h2[n>>1]);
          float cn = (n&1) ? __high2float(h2[(12+n)>>1]) : __low2float(h2[(12+n)>>1]);
          h[n] = fmaf(dA, h[n], du*bn);
          y = fmaf(h[n], cn, y);
        }
      }
      float ss = y*y;
      #pragma unroll
      for (int m=1;m<64;m<<=1) ss += __shfl_xor(ss, m, 64);
      float yn = rsc * rsqrtf(ss*(1.f/64.f) + 1e-5f) * y;
      out[p*DD+d] = yn * __half2float(gz[i]);
    }
  }
}

extern "C" void kernel_launch(void* const* d_in, const int* in_sizes, int n_in,
                              void* d_out, int out_size, void* d_ws, size_t ws_size,
                              hipStream_t stream) {
  const float* x     = (const float*)d_in[0];
  const float* w     = (const float*)d_in[1];
  const float* gamma = (const float*)d_in[2];
  const float* beta  = (const float*)d_in[3];
  const float* xpw   = (const float*)d_in[4];
  const float* dtw   = (const float*)d_in[5];
  const float* dtb   = (const float*)d_in[6];
  const float* Alog  = (const float*)d_in[7];
  const float* Dsv   = (const float*)d_in[8];
  const float* rmss  = (const float*)d_in[9];
  float* out = (float*)d_out;

  float* f = (float*)d_ws;
  const size_t n_xld = (size_t)NB*LL*DD;       // 4,194,304
  __half*  xc   = (__half*)f;                  // [0, n_xld) halfs
  __half*  gate = xc + n_xld;                  // [n_xld, 2*n_xld) halfs
  __half2* duo  = (__half2*)(f + n_xld);       // n_xld half2
  __half*  bch  = (__half*)(f + 2*n_xld);      // NB*LL*24 halfs
  float* chunkst = f + 2*n_xld + (size_t)NB*LL*24/2 + 1024;  // f32 (b,c,d,12)
  __half* hin   = (__half*)(chunkst + (size_t)NB*NC*64*12);  // 16-half records
  float* bn_part = chunkst + (size_t)NB*NC*64*12 + (size_t)NB*NC*64*8;  // 512x128
  float* bnp     = bn_part + (size_t)NCB*128;  // sc[64], sh[64]

  k_conv   <<<NCB, 512, 0, stream>>>(x, w, xc, gate, bn_part);
  k_bnred  <<<1, 512, 0, stream>>>(bn_part, gamma, beta, bnp);
  k_proj   <<<NB*(LL/PJ), 256, 0, stream>>>(xc, bnp, xpw, dtw, dtb, Alog, duo, bch, chunkst);
  k_scanMid<<<NB*DD, 128, 0, stream>>>(chunkst, Alog, hin);
  k_scanB  <<<(NB*NC)/4, 256, 0, stream>>>(duo, bch, Alog, hin, Dsv, rmss, gate, out);
}